// Round 1
// baseline (1035.707 us; speedup 1.0000x reference)
//
#include <hip/hip_runtime.h>
#include <math.h>

#define LTOT 2048
#define MROWS 4096   // BATCH * LTOT

// ---------------------------------------------------------------------------
// SGEMM (fp32): C[m,n] = sum_k A[m,k] * W[n,k]  (W row-major [N][K])
// 128x128 tile, TK=16, 256 threads, 8x8 microtile.
// ---------------------------------------------------------------------------

__global__ __launch_bounds__(256) void k_inproj(const float* __restrict__ x,
    const float* __restrict__ w, const float* __restrict__ bias,
    float* __restrict__ xp)
{
  __shared__ float As[16][132];
  __shared__ float Bs[16][132];
  const int t = threadIdx.x;
  const int m0 = blockIdx.y * 128;
  const int n0 = blockIdx.x * 128;
  const int lrow = t >> 2;            // 0..63
  const int lc4  = (t & 3) * 4;       // 0,4,8,12
  const int tx = t & 15, ty = t >> 4;

  float acc[8][8];
  #pragma unroll
  for (int i = 0; i < 8; ++i)
    #pragma unroll
    for (int j = 0; j < 8; ++j) acc[i][j] = 0.f;

  const float* Ar0 = x + (size_t)(m0 + lrow) * 1024;
  const float* Ar1 = x + (size_t)(m0 + lrow + 64) * 1024;
  const float* Wr0 = w + (size_t)(n0 + lrow) * 1024;
  const float* Wr1 = w + (size_t)(n0 + lrow + 64) * 1024;

  for (int k0 = 0; k0 < 1024; k0 += 16) {
    float4 a0 = *(const float4*)(Ar0 + k0 + lc4);
    float4 a1 = *(const float4*)(Ar1 + k0 + lc4);
    float4 b0 = *(const float4*)(Wr0 + k0 + lc4);
    float4 b1 = *(const float4*)(Wr1 + k0 + lc4);
    __syncthreads();
    As[lc4+0][lrow] = a0.x; As[lc4+1][lrow] = a0.y; As[lc4+2][lrow] = a0.z; As[lc4+3][lrow] = a0.w;
    As[lc4+0][lrow+64] = a1.x; As[lc4+1][lrow+64] = a1.y; As[lc4+2][lrow+64] = a1.z; As[lc4+3][lrow+64] = a1.w;
    Bs[lc4+0][lrow] = b0.x; Bs[lc4+1][lrow] = b0.y; Bs[lc4+2][lrow] = b0.z; Bs[lc4+3][lrow] = b0.w;
    Bs[lc4+0][lrow+64] = b1.x; Bs[lc4+1][lrow+64] = b1.y; Bs[lc4+2][lrow+64] = b1.z; Bs[lc4+3][lrow+64] = b1.w;
    __syncthreads();
    #pragma unroll
    for (int k = 0; k < 16; ++k) {
      float4 av0 = *(const float4*)&As[k][ty*8];
      float4 av1 = *(const float4*)&As[k][ty*8+4];
      float4 bv0 = *(const float4*)&Bs[k][tx*8];
      float4 bv1 = *(const float4*)&Bs[k][tx*8+4];
      float av[8] = {av0.x,av0.y,av0.z,av0.w,av1.x,av1.y,av1.z,av1.w};
      float bv[8] = {bv0.x,bv0.y,bv0.z,bv0.w,bv1.x,bv1.y,bv1.z,bv1.w};
      #pragma unroll
      for (int i = 0; i < 8; ++i)
        #pragma unroll
        for (int j = 0; j < 8; ++j)
          acc[i][j] = fmaf(av[i], bv[j], acc[i][j]);
    }
  }

  float4 bb0 = *(const float4*)&bias[n0 + tx*8];
  float4 bb1 = *(const float4*)&bias[n0 + tx*8 + 4];
  #pragma unroll
  for (int i = 0; i < 8; ++i) {
    const int m = m0 + ty*8 + i;
    float4 o0 = {acc[i][0]+bb0.x, acc[i][1]+bb0.y, acc[i][2]+bb0.z, acc[i][3]+bb0.w};
    float4 o1 = {acc[i][4]+bb1.x, acc[i][5]+bb1.y, acc[i][6]+bb1.z, acc[i][7]+bb1.w};
    *(float4*)&xp[(size_t)m*2048 + n0 + tx*8]     = o0;
    *(float4*)&xp[(size_t)m*2048 + n0 + tx*8 + 4] = o1;
  }
}

__device__ __forceinline__ float softplus_f(float x) {
  return (x > 15.f) ? x : log1pf(expf(x));
}

// Fused delta (N=1024, softplus) and B (N=128, +bias) GEMM. A = xp[:, :1024], lda=2048.
__global__ __launch_bounds__(256) void k_deltab(const float* __restrict__ xp,
    const float* __restrict__ dw, const float* __restrict__ bw, const float* __restrict__ bb,
    float* __restrict__ delta, float* __restrict__ Bm)
{
  __shared__ float As[16][132];
  __shared__ float Bs[16][132];
  const int t = threadIdx.x;
  const int m0 = blockIdx.y * 128;
  const int nt = blockIdx.x;          // 0..8
  const bool isB = (nt == 8);
  const int n0 = nt * 128;
  const float* W = isB ? bw : (dw + (size_t)n0 * 1024);
  const int lrow = t >> 2;
  const int lc4  = (t & 3) * 4;
  const int tx = t & 15, ty = t >> 4;

  float acc[8][8];
  #pragma unroll
  for (int i = 0; i < 8; ++i)
    #pragma unroll
    for (int j = 0; j < 8; ++j) acc[i][j] = 0.f;

  const float* Ar0 = xp + (size_t)(m0 + lrow) * 2048;
  const float* Ar1 = xp + (size_t)(m0 + lrow + 64) * 2048;
  const float* Wr0 = W + (size_t)lrow * 1024;
  const float* Wr1 = W + (size_t)(lrow + 64) * 1024;

  for (int k0 = 0; k0 < 1024; k0 += 16) {
    float4 a0 = *(const float4*)(Ar0 + k0 + lc4);
    float4 a1 = *(const float4*)(Ar1 + k0 + lc4);
    float4 b0 = *(const float4*)(Wr0 + k0 + lc4);
    float4 b1 = *(const float4*)(Wr1 + k0 + lc4);
    __syncthreads();
    As[lc4+0][lrow] = a0.x; As[lc4+1][lrow] = a0.y; As[lc4+2][lrow] = a0.z; As[lc4+3][lrow] = a0.w;
    As[lc4+0][lrow+64] = a1.x; As[lc4+1][lrow+64] = a1.y; As[lc4+2][lrow+64] = a1.z; As[lc4+3][lrow+64] = a1.w;
    Bs[lc4+0][lrow] = b0.x; Bs[lc4+1][lrow] = b0.y; Bs[lc4+2][lrow] = b0.z; Bs[lc4+3][lrow] = b0.w;
    Bs[lc4+0][lrow+64] = b1.x; Bs[lc4+1][lrow+64] = b1.y; Bs[lc4+2][lrow+64] = b1.z; Bs[lc4+3][lrow+64] = b1.w;
    __syncthreads();
    #pragma unroll
    for (int k = 0; k < 16; ++k) {
      float4 av0 = *(const float4*)&As[k][ty*8];
      float4 av1 = *(const float4*)&As[k][ty*8+4];
      float4 bv0 = *(const float4*)&Bs[k][tx*8];
      float4 bv1 = *(const float4*)&Bs[k][tx*8+4];
      float av[8] = {av0.x,av0.y,av0.z,av0.w,av1.x,av1.y,av1.z,av1.w};
      float bv[8] = {bv0.x,bv0.y,bv0.z,bv0.w,bv1.x,bv1.y,bv1.z,bv1.w};
      #pragma unroll
      for (int i = 0; i < 8; ++i)
        #pragma unroll
        for (int j = 0; j < 8; ++j)
          acc[i][j] = fmaf(av[i], bv[j], acc[i][j]);
    }
  }

  if (!isB) {
    #pragma unroll
    for (int i = 0; i < 8; ++i) {
      const int m = m0 + ty*8 + i;
      float* dst = delta + (size_t)m*1024 + n0 + tx*8;
      #pragma unroll
      for (int j = 0; j < 8; ++j) dst[j] = softplus_f(acc[i][j]);
    }
  } else {
    #pragma unroll
    for (int i = 0; i < 8; ++i) {
      const int m = m0 + ty*8 + i;
      float* dst = Bm + (size_t)m*128 + tx*8;
      #pragma unroll
      for (int j = 0; j < 8; ++j) dst[j] = acc[i][j] + bb[tx*8 + j];
    }
  }
}

// ---------------------------------------------------------------------------
// Depthwise causal conv (K=4) + silu. Reads u = xp[:, :1024], writes uc.
// ---------------------------------------------------------------------------
__global__ void k_conv(const float* __restrict__ xp, const float* __restrict__ cw,
    const float* __restrict__ cb, float* __restrict__ uc)
{
  const int e = blockIdx.x * 256 + threadIdx.x;   // [0, 4096*1024)
  const int m = e >> 10;
  const int d = e & 1023;
  const int l = m & (LTOT - 1);
  float a = cb[d];
  #pragma unroll
  for (int j = 0; j < 4; ++j) {
    const int lj = l - 3 + j;
    if (lj >= 0)
      a = fmaf(xp[(size_t)(m - 3 + j) * 2048 + d], cw[d*4 + j], a);
  }
  uc[e] = a / (1.f + expf(-a));
}

// ---------------------------------------------------------------------------
// Selective scan + final y * silu(v).
// Block = 256 threads = 16 groups of 16 lanes; group handles one (b,d); lane = state n.
// L is processed in chunks of 64 staged in LDS (double buffered).
// uc lives in d_out and is overwritten in place with the final output.
// ---------------------------------------------------------------------------
__global__ __launch_bounds__(256) void k_scan(
    const float* __restrict__ xp, const float* __restrict__ delta,
    const float* __restrict__ Bm, const float* __restrict__ a_log,
    const float* __restrict__ cp, const float* uc, float* out)
{
  __shared__ float sd[2][64][16];
  __shared__ float su[2][64][16];
  __shared__ float sb[2][64][16];
  __shared__ float sv[2][64][16];
  const int t  = threadIdx.x;
  const int p0 = blockIdx.x * 16;     // (b,d) pair base
  const int b  = p0 >> 10;
  const int d0 = p0 & 1023;
  const int g  = d0 >> 7;             // shared by all 16 d's in this block
  const int gi = t >> 4;              // which d
  const int n  = t & 15;              // state
  const int d  = d0 + gi;

  const float A2 = -expf(a_log[d*16 + n]) * 1.4426950408889634f;  // A * log2(e)
  const float cc = cp[d*16 + n];

  const int lrow = t >> 2;            // 0..63
  const int lc4  = (t & 3) * 4;
  const size_t mb = (size_t)b * LTOT;

  float4 rd, ru, rb, rv;
  auto LOAD = [&](int l0) {
    const size_t r = mb + l0 + lrow;
    rd = *(const float4*)&delta[r*1024 + d0 + lc4];
    ru = *(const float4*)&uc[r*1024 + d0 + lc4];
    rv = *(const float4*)&xp[r*2048 + 1024 + d0 + lc4];
    rb = *(const float4*)&Bm[r*128 + g*16 + lc4];
  };
  auto STORE = [&](int buf) {
    *(float4*)&sd[buf][lrow][lc4] = rd;
    *(float4*)&su[buf][lrow][lc4] = ru;
    *(float4*)&sv[buf][lrow][lc4] = rv;
    *(float4*)&sb[buf][lrow][lc4] = rb;
  };

  LOAD(0); STORE(0);
  __syncthreads();

  float h = 0.f;
  const int NC = LTOT / 64;
  for (int c = 0; c < NC; ++c) {
    if (c + 1 < NC) LOAD((c + 1) * 64);
    const int cb_ = c & 1;
    #pragma unroll 4
    for (int l = 0; l < 64; ++l) {
      const float dv = sd[cb_][l][gi];
      const float uv = su[cb_][l][gi];
      const float bv = sb[cb_][l][n];
      const float da = exp2f(dv * A2);
      h = fmaf(da, h, dv * uv * bv);
      float p = h * cc;
      p += __shfl_xor(p, 8, 16);
      p += __shfl_xor(p, 4, 16);
      p += __shfl_xor(p, 2, 16);
      p += __shfl_xor(p, 1, 16);
      if (n == 0) {
        const float vv = sv[cb_][l][gi];
        out[(mb + c*64 + l) * 1024 + d] = p * (vv / (1.f + expf(-vv)));
      }
    }
    if (c + 1 < NC) STORE((c + 1) & 1);
    __syncthreads();
  }
}

// ---------------------------------------------------------------------------
extern "C" void kernel_launch(void* const* d_in, const int* in_sizes, int n_in,
                              void* d_out, int out_size, void* d_ws, size_t ws_size,
                              hipStream_t stream) {
  const float* x    = (const float*)d_in[0];
  const float* w1   = (const float*)d_in[1];
  const float* b1   = (const float*)d_in[2];
  const float* dw   = (const float*)d_in[3];
  const float* alog = (const float*)d_in[4];
  const float* bw   = (const float*)d_in[5];
  const float* bb   = (const float*)d_in[6];
  const float* cp   = (const float*)d_in[7];
  const float* cw   = (const float*)d_in[8];
  const float* cb   = (const float*)d_in[9];
  float* out = (float*)d_out;

  float* xp    = (float*)d_ws;                        // [4096][2048]  32 MB
  float* delta = xp + (size_t)MROWS * 2048;           // [4096][1024]  16 MB
  float* Bm    = delta + (size_t)MROWS * 1024;        // [4096][128]    2 MB

  k_inproj<<<dim3(16, 32), 256, 0, stream>>>(x, w1, b1, xp);
  k_deltab<<<dim3(9, 32), 256, 0, stream>>>(xp, dw, bw, bb, delta, Bm);
  k_conv<<<(MROWS * 1024) / 256, 256, 0, stream>>>(xp, cw, cb, out);   // out <- u_conv
  k_scan<<<MROWS / 2 / 16, 256, 0, stream>>>(xp, delta, Bm, alog, cp, out, out);
}

// Round 2
// 501.768 us; speedup vs baseline: 2.0641x; 2.0641x over previous
//
#include <hip/hip_runtime.h>
#include <math.h>

#define LTOT 2048
#define MROWS 4096   // BATCH * LTOT
#define CHK 64
#define NCH (LTOT / CHK)   // 32

// ---------------------------------------------------------------------------
// SGEMM (fp32): C[m,n] = sum_k A[m,k] * W[n,k]  (W row-major [N][K])
// 128x128 tile, TK=16, 256 threads, 8x8 microtile.
// ---------------------------------------------------------------------------

__global__ __launch_bounds__(256) void k_inproj(const float* __restrict__ x,
    const float* __restrict__ w, const float* __restrict__ bias,
    float* __restrict__ xp)
{
  __shared__ float As[16][132];
  __shared__ float Bs[16][132];
  const int t = threadIdx.x;
  const int m0 = blockIdx.y * 128;
  const int n0 = blockIdx.x * 128;
  const int lrow = t >> 2;            // 0..63
  const int lc4  = (t & 3) * 4;       // 0,4,8,12
  const int tx = t & 15, ty = t >> 4;

  float acc[8][8];
  #pragma unroll
  for (int i = 0; i < 8; ++i)
    #pragma unroll
    for (int j = 0; j < 8; ++j) acc[i][j] = 0.f;

  const float* Ar0 = x + (size_t)(m0 + lrow) * 1024;
  const float* Ar1 = x + (size_t)(m0 + lrow + 64) * 1024;
  const float* Wr0 = w + (size_t)(n0 + lrow) * 1024;
  const float* Wr1 = w + (size_t)(n0 + lrow + 64) * 1024;

  for (int k0 = 0; k0 < 1024; k0 += 16) {
    float4 a0 = *(const float4*)(Ar0 + k0 + lc4);
    float4 a1 = *(const float4*)(Ar1 + k0 + lc4);
    float4 b0 = *(const float4*)(Wr0 + k0 + lc4);
    float4 b1 = *(const float4*)(Wr1 + k0 + lc4);
    __syncthreads();
    As[lc4+0][lrow] = a0.x; As[lc4+1][lrow] = a0.y; As[lc4+2][lrow] = a0.z; As[lc4+3][lrow] = a0.w;
    As[lc4+0][lrow+64] = a1.x; As[lc4+1][lrow+64] = a1.y; As[lc4+2][lrow+64] = a1.z; As[lc4+3][lrow+64] = a1.w;
    Bs[lc4+0][lrow] = b0.x; Bs[lc4+1][lrow] = b0.y; Bs[lc4+2][lrow] = b0.z; Bs[lc4+3][lrow] = b0.w;
    Bs[lc4+0][lrow+64] = b1.x; Bs[lc4+1][lrow+64] = b1.y; Bs[lc4+2][lrow+64] = b1.z; Bs[lc4+3][lrow+64] = b1.w;
    __syncthreads();
    #pragma unroll
    for (int k = 0; k < 16; ++k) {
      float4 av0 = *(const float4*)&As[k][ty*8];
      float4 av1 = *(const float4*)&As[k][ty*8+4];
      float4 bv0 = *(const float4*)&Bs[k][tx*8];
      float4 bv1 = *(const float4*)&Bs[k][tx*8+4];
      float av[8] = {av0.x,av0.y,av0.z,av0.w,av1.x,av1.y,av1.z,av1.w};
      float bv[8] = {bv0.x,bv0.y,bv0.z,bv0.w,bv1.x,bv1.y,bv1.z,bv1.w};
      #pragma unroll
      for (int i = 0; i < 8; ++i)
        #pragma unroll
        for (int j = 0; j < 8; ++j)
          acc[i][j] = fmaf(av[i], bv[j], acc[i][j]);
    }
  }

  float4 bb0 = *(const float4*)&bias[n0 + tx*8];
  float4 bb1 = *(const float4*)&bias[n0 + tx*8 + 4];
  #pragma unroll
  for (int i = 0; i < 8; ++i) {
    const int m = m0 + ty*8 + i;
    float4 o0 = {acc[i][0]+bb0.x, acc[i][1]+bb0.y, acc[i][2]+bb0.z, acc[i][3]+bb0.w};
    float4 o1 = {acc[i][4]+bb1.x, acc[i][5]+bb1.y, acc[i][6]+bb1.z, acc[i][7]+bb1.w};
    *(float4*)&xp[(size_t)m*2048 + n0 + tx*8]     = o0;
    *(float4*)&xp[(size_t)m*2048 + n0 + tx*8 + 4] = o1;
  }
}

__device__ __forceinline__ float softplus_f(float x) {
  return (x > 15.f) ? x : log1pf(expf(x));
}

// Fused delta (N=1024, softplus) and B (N=128, +bias) GEMM. A = xp[:, :1024], lda=2048.
__global__ __launch_bounds__(256) void k_deltab(const float* __restrict__ xp,
    const float* __restrict__ dw, const float* __restrict__ bw, const float* __restrict__ bb,
    float* __restrict__ delta, float* __restrict__ Bm)
{
  __shared__ float As[16][132];
  __shared__ float Bs[16][132];
  const int t = threadIdx.x;
  const int m0 = blockIdx.y * 128;
  const int nt = blockIdx.x;          // 0..8
  const bool isB = (nt == 8);
  const int n0 = nt * 128;
  const float* W = isB ? bw : (dw + (size_t)n0 * 1024);
  const int lrow = t >> 2;
  const int lc4  = (t & 3) * 4;
  const int tx = t & 15, ty = t >> 4;

  float acc[8][8];
  #pragma unroll
  for (int i = 0; i < 8; ++i)
    #pragma unroll
    for (int j = 0; j < 8; ++j) acc[i][j] = 0.f;

  const float* Ar0 = xp + (size_t)(m0 + lrow) * 2048;
  const float* Ar1 = xp + (size_t)(m0 + lrow + 64) * 2048;
  const float* Wr0 = W + (size_t)lrow * 1024;
  const float* Wr1 = W + (size_t)(lrow + 64) * 1024;

  for (int k0 = 0; k0 < 1024; k0 += 16) {
    float4 a0 = *(const float4*)(Ar0 + k0 + lc4);
    float4 a1 = *(const float4*)(Ar1 + k0 + lc4);
    float4 b0 = *(const float4*)(Wr0 + k0 + lc4);
    float4 b1 = *(const float4*)(Wr1 + k0 + lc4);
    __syncthreads();
    As[lc4+0][lrow] = a0.x; As[lc4+1][lrow] = a0.y; As[lc4+2][lrow] = a0.z; As[lc4+3][lrow] = a0.w;
    As[lc4+0][lrow+64] = a1.x; As[lc4+1][lrow+64] = a1.y; As[lc4+2][lrow+64] = a1.z; As[lc4+3][lrow+64] = a1.w;
    Bs[lc4+0][lrow] = b0.x; Bs[lc4+1][lrow] = b0.y; Bs[lc4+2][lrow] = b0.z; Bs[lc4+3][lrow] = b0.w;
    Bs[lc4+0][lrow+64] = b1.x; Bs[lc4+1][lrow+64] = b1.y; Bs[lc4+2][lrow+64] = b1.z; Bs[lc4+3][lrow+64] = b1.w;
    __syncthreads();
    #pragma unroll
    for (int k = 0; k < 16; ++k) {
      float4 av0 = *(const float4*)&As[k][ty*8];
      float4 av1 = *(const float4*)&As[k][ty*8+4];
      float4 bv0 = *(const float4*)&Bs[k][tx*8];
      float4 bv1 = *(const float4*)&Bs[k][tx*8+4];
      float av[8] = {av0.x,av0.y,av0.z,av0.w,av1.x,av1.y,av1.z,av1.w};
      float bv[8] = {bv0.x,bv0.y,bv0.z,bv0.w,bv1.x,bv1.y,bv1.z,bv1.w};
      #pragma unroll
      for (int i = 0; i < 8; ++i)
        #pragma unroll
        for (int j = 0; j < 8; ++j)
          acc[i][j] = fmaf(av[i], bv[j], acc[i][j]);
    }
  }

  if (!isB) {
    #pragma unroll
    for (int i = 0; i < 8; ++i) {
      const int m = m0 + ty*8 + i;
      float* dst = delta + (size_t)m*1024 + n0 + tx*8;
      #pragma unroll
      for (int j = 0; j < 8; ++j) dst[j] = softplus_f(acc[i][j]);
    }
  } else {
    #pragma unroll
    for (int i = 0; i < 8; ++i) {
      const int m = m0 + ty*8 + i;
      float* dst = Bm + (size_t)m*128 + tx*8;
      #pragma unroll
      for (int j = 0; j < 8; ++j) dst[j] = acc[i][j] + bb[tx*8 + j];
    }
  }
}

// ---------------------------------------------------------------------------
// Depthwise causal conv (K=4) + silu. Reads u = xp[:, :1024], writes uc (d_out).
// ---------------------------------------------------------------------------
__global__ void k_conv(const float* __restrict__ xp, const float* __restrict__ cw,
    const float* __restrict__ cb, float* __restrict__ uc)
{
  const int e = blockIdx.x * 256 + threadIdx.x;   // [0, 4096*1024)
  const int m = e >> 10;
  const int d = e & 1023;
  const int l = m & (LTOT - 1);
  float a = cb[d];
  #pragma unroll
  for (int j = 0; j < 4; ++j) {
    const int lj = l - 3 + j;
    if (lj >= 0)
      a = fmaf(xp[(size_t)(m - 3 + j) * 2048 + d], cw[d*4 + j], a);
  }
  uc[e] = a / (1.f + expf(-a));
}

// ---------------------------------------------------------------------------
// Chunk-parallel selective scan.
// Unit = (b, chunk, d); 16 lanes per unit (lane = state n). Block = 256 thr =
// 16 units (16 consecutive d). Grid = B * NCH * (D/16) = 4096 blocks.
// Phase A: per-chunk local scan from h=0 -> h_end, P = prod(da).
// Phase B: sequential combine over 32 chunks (per (b,d,n) strand).
// Phase C: re-run chunks from true start state, reduce over n, apply silu(v).
// ---------------------------------------------------------------------------

#define SPAD 20   // LDS row pad (bank spread + float4-aligned: 80B rows)

__global__ __launch_bounds__(256) void k_scanA(
    const float* __restrict__ delta, const float* __restrict__ uc,
    const float* __restrict__ Bm, const float* __restrict__ a_log,
    float* __restrict__ hend, float* __restrict__ Pp)
{
  __shared__ float sd[CHK][SPAD];
  __shared__ float su[CHK][SPAD];
  __shared__ float sb[CHK][SPAD];
  const int t = threadIdx.x;
  const int bid = blockIdx.x;
  const int dblk = bid & 63;
  const int ch   = (bid >> 6) & (NCH - 1);
  const int b    = bid >> 11;
  const int d0 = dblk * 16;
  const int g  = dblk >> 3;
  const int l0 = ch * CHK;
  const size_t mb = (size_t)b * LTOT;

  // stage chunk: 64 rows x 16 floats per array
  {
    const int lrow = t >> 2;
    const int lc4  = (t & 3) * 4;
    const size_t r = mb + l0 + lrow;
    float4 rd = *(const float4*)&delta[r*1024 + d0 + lc4];
    float4 ru = *(const float4*)&uc[r*1024 + d0 + lc4];
    float4 rb = *(const float4*)&Bm[r*128 + g*16 + lc4];
    *(float4*)&sd[lrow][lc4] = rd;
    *(float4*)&su[lrow][lc4] = ru;
    *(float4*)&sb[lrow][lc4] = rb;
  }
  __syncthreads();

  const int gi = t >> 4;
  const int n  = t & 15;
  const int d  = d0 + gi;
  const float A2 = -expf(a_log[d*16 + n]) * 1.4426950408889634f;

  float h = 0.f, P = 1.f;
  #pragma unroll 8
  for (int l = 0; l < CHK; ++l) {
    const float dv = sd[l][gi];
    const float uv = su[l][gi];
    const float bv = sb[l][n];
    const float da = exp2f(dv * A2);
    P *= da;
    h = fmaf(da, h, dv * uv * bv);
  }
  const size_t idx = ((size_t)(b*NCH + ch) * 1024 + d) * 16 + n;
  hend[idx] = h;
  Pp[idx]   = P;
}

__global__ void k_scanB(float* hP /* hend in, Hstart out (aliased) */,
                        const float* __restrict__ Pp)
{
  const int t = blockIdx.x * 256 + threadIdx.x;   // 32768 strands
  const int b  = t >> 14;
  const int dn = t & 16383;
  float H = 0.f;
  for (int ch = 0; ch < NCH; ++ch) {
    const size_t idx = ((size_t)(b*NCH + ch) << 14) + dn;
    const float he = hP[idx];
    const float P  = Pp[idx];
    hP[idx] = H;              // exclusive prefix: start state of chunk ch
    H = fmaf(P, H, he);
  }
}

__global__ __launch_bounds__(256) void k_scanC(
    const float* __restrict__ xp, const float* __restrict__ delta,
    const float* __restrict__ uc, const float* __restrict__ Bm,
    const float* __restrict__ a_log, const float* __restrict__ cp,
    const float* __restrict__ Hstart, float* __restrict__ out)
{
  __shared__ float sd[CHK][SPAD];
  __shared__ float su[CHK][SPAD];
  __shared__ float sb[CHK][SPAD];
  __shared__ float sv[CHK][SPAD];
  __shared__ float sy[CHK][SPAD];
  const int t = threadIdx.x;
  const int bid = blockIdx.x;
  const int dblk = bid & 63;
  const int ch   = (bid >> 6) & (NCH - 1);
  const int b    = bid >> 11;
  const int d0 = dblk * 16;
  const int g  = dblk >> 3;
  const int l0 = ch * CHK;
  const size_t mb = (size_t)b * LTOT;

  {
    const int lrow = t >> 2;
    const int lc4  = (t & 3) * 4;
    const size_t r = mb + l0 + lrow;
    float4 rd = *(const float4*)&delta[r*1024 + d0 + lc4];
    float4 ru = *(const float4*)&uc[r*1024 + d0 + lc4];
    float4 rv = *(const float4*)&xp[r*2048 + 1024 + d0 + lc4];
    float4 rb = *(const float4*)&Bm[r*128 + g*16 + lc4];
    *(float4*)&sd[lrow][lc4] = rd;
    *(float4*)&su[lrow][lc4] = ru;
    *(float4*)&sv[lrow][lc4] = rv;
    *(float4*)&sb[lrow][lc4] = rb;
  }
  __syncthreads();

  const int gi = t >> 4;
  const int n  = t & 15;
  const int d  = d0 + gi;
  const float A2 = -expf(a_log[d*16 + n]) * 1.4426950408889634f;
  const float cc = cp[d*16 + n];
  float h = Hstart[((size_t)(b*NCH + ch) * 1024 + d) * 16 + n];

  #pragma unroll
  for (int l16 = 0; l16 < CHK; l16 += 16) {
    float p[16];
    #pragma unroll
    for (int j = 0; j < 16; ++j) {
      const int l = l16 + j;
      const float dv = sd[l][gi];
      const float uv = su[l][gi];
      const float bv = sb[l][n];
      const float da = exp2f(dv * A2);
      h = fmaf(da, h, dv * uv * bv);
      p[j] = h * cc;
    }
    // reduce-scatter butterfly over n within each 16-lane group:
    // after 4 stages, lane n holds sum over states for timestep l16+n.
    float q8[8];
    #pragma unroll
    for (int j = 0; j < 8; ++j) {
      const float send = (n & 8) ? p[j]     : p[j + 8];
      const float keep = (n & 8) ? p[j + 8] : p[j];
      q8[j] = keep + __shfl_xor(send, 8, 16);
    }
    float q4[4];
    #pragma unroll
    for (int j = 0; j < 4; ++j) {
      const float send = (n & 4) ? q8[j]     : q8[j + 4];
      const float keep = (n & 4) ? q8[j + 4] : q8[j];
      q4[j] = keep + __shfl_xor(send, 4, 16);
    }
    float q2[2];
    #pragma unroll
    for (int j = 0; j < 2; ++j) {
      const float send = (n & 2) ? q4[j]     : q4[j + 2];
      const float keep = (n & 2) ? q4[j + 2] : q4[j];
      q2[j] = keep + __shfl_xor(send, 2, 16);
    }
    {
      const float send = (n & 1) ? q2[0] : q2[1];
      const float keep = (n & 1) ? q2[1] : q2[0];
      sy[l16 + n][gi] = keep + __shfl_xor(send, 1, 16);
    }
  }

  __syncthreads();
  // coalesced epilogue: y * silu(v)
  const int rr = t >> 4;   // 0..15
  const int c  = t & 15;
  #pragma unroll
  for (int k = 0; k < 4; ++k) {
    const int r = rr + k * 16;
    const float vv = sv[r][c];
    out[(mb + l0 + r) * 1024 + d0 + c] = sy[r][c] * (vv / (1.f + expf(-vv)));
  }
}

// ---------------------------------------------------------------------------
extern "C" void kernel_launch(void* const* d_in, const int* in_sizes, int n_in,
                              void* d_out, int out_size, void* d_ws, size_t ws_size,
                              hipStream_t stream) {
  const float* x    = (const float*)d_in[0];
  const float* w1   = (const float*)d_in[1];
  const float* b1   = (const float*)d_in[2];
  const float* dw   = (const float*)d_in[3];
  const float* alog = (const float*)d_in[4];
  const float* bw   = (const float*)d_in[5];
  const float* bb   = (const float*)d_in[6];
  const float* cp   = (const float*)d_in[7];
  const float* cw   = (const float*)d_in[8];
  const float* cb   = (const float*)d_in[9];
  float* out = (float*)d_out;

  float* xp    = (float*)d_ws;                        // [4096][2048]  32 MB
  float* delta = xp + (size_t)MROWS * 2048;           // [4096][1024]  16 MB
  float* Bm    = delta + (size_t)MROWS * 1024;        // [4096][128]    2 MB
  float* hend  = Bm + (size_t)MROWS * 128;            // [B][NCH][D][16] 4 MB (also Hstart)
  float* Pp    = hend + (size_t)2 * NCH * 1024 * 16;  // [B][NCH][D][16] 4 MB

  k_inproj<<<dim3(16, 32), 256, 0, stream>>>(x, w1, b1, xp);
  k_deltab<<<dim3(9, 32), 256, 0, stream>>>(xp, dw, bw, bb, delta, Bm);
  k_conv<<<(MROWS * 1024) / 256, 256, 0, stream>>>(xp, cw, cb, out);   // out <- u_conv
  k_scanA<<<2 * NCH * 64, 256, 0, stream>>>(delta, out, Bm, alog, hend, Pp);
  k_scanB<<<128, 256, 0, stream>>>(hend, Pp);
  k_scanC<<<2 * NCH * 64, 256, 0, stream>>>(xp, delta, out, Bm, alog, cp, hend, out);
}

// Round 3
// 238.554 us; speedup vs baseline: 4.3416x; 2.1034x over previous
//
#include <hip/hip_runtime.h>
#include <math.h>

#define LTOT 2048
#define MROWS 4096   // BATCH * LTOT
#define CHK 64
#define NCH (LTOT / CHK)   // 32

typedef short bf16x8 __attribute__((ext_vector_type(8)));
typedef float f32x4  __attribute__((ext_vector_type(4)));

__device__ __forceinline__ unsigned short bf16_rne(float f) {
  unsigned u = __float_as_uint(f);
  u += 0x7FFF + ((u >> 16) & 1);
  return (unsigned short)(u >> 16);
}
__device__ __forceinline__ float bf16_to_f(unsigned short h) {
  return __uint_as_float(((unsigned)h) << 16);
}
__device__ __forceinline__ float softplus_f(float x) {
  return (x > 15.f) ? x : log1pf(expf(x));
}

// ---------------------------------------------------------------------------
// fp32 -> (hi, lo) bf16 split, elementwise (4 elems/thread).
// ---------------------------------------------------------------------------
__global__ void k_cvt(const float* __restrict__ src, unsigned short* __restrict__ h,
                      unsigned short* __restrict__ l, int n4) {
  const int i = blockIdx.x * 256 + threadIdx.x;
  if (i >= n4) return;
  const float4 v = ((const float4*)src)[i];
  ushort4 hh, ll;
  hh.x = bf16_rne(v.x); ll.x = bf16_rne(v.x - bf16_to_f(hh.x));
  hh.y = bf16_rne(v.y); ll.y = bf16_rne(v.y - bf16_to_f(hh.y));
  hh.z = bf16_rne(v.z); ll.z = bf16_rne(v.z - bf16_to_f(hh.z));
  hh.w = bf16_rne(v.w); ll.w = bf16_rne(v.w - bf16_to_f(hh.w));
  ((ushort4*)h)[i] = hh;
  ((ushort4*)l)[i] = ll;
}

// u = xp[:, :1024] (stride 2048) -> uh/ul [4096][1024]
__global__ void k_cvt_u(const float* __restrict__ xp, unsigned short* __restrict__ uh,
                        unsigned short* __restrict__ ul) {
  const int i = blockIdx.x * 256 + threadIdx.x;   // 1,048,576
  const int m = i >> 8;
  const int c = (i & 255) * 4;
  const float4 v = *(const float4*)&xp[(size_t)m * 2048 + c];
  ushort4 hh, ll;
  hh.x = bf16_rne(v.x); ll.x = bf16_rne(v.x - bf16_to_f(hh.x));
  hh.y = bf16_rne(v.y); ll.y = bf16_rne(v.y - bf16_to_f(hh.y));
  hh.z = bf16_rne(v.z); ll.z = bf16_rne(v.z - bf16_to_f(hh.z));
  hh.w = bf16_rne(v.w); ll.w = bf16_rne(v.w - bf16_to_f(hh.w));
  *(ushort4*)&uh[(size_t)m * 1024 + c] = hh;
  *(ushort4*)&ul[(size_t)m * 1024 + c] = ll;
}

// ---------------------------------------------------------------------------
// Split-bf16 MFMA GEMM: C = Ah*Bh + Ah*Bl + Al*Bh  (~fp32 precision)
// A: [M][1024] row-major bf16 (hi/lo), B(W): [N][1024] row-major bf16 (hi/lo)
// 128x128 tile, BK=32, 256 thr = 4 waves (2x2), 4x4 frags of 16x16x32 / wave.
// MODE 0: out0 = xp (stride 2048), bias added.
// MODE 1: n-tile<8 -> out0 = delta (softplus); n-tile==8 -> out1 = Bm (+bias).
// ---------------------------------------------------------------------------
template<int MODE>
__global__ __launch_bounds__(256) void k_gemm(
    const unsigned short* __restrict__ Ah_g, const unsigned short* __restrict__ Al_g,
    const unsigned short* __restrict__ Bh_g, const unsigned short* __restrict__ Bl_g,
    const float* __restrict__ bias, float* __restrict__ out0, float* __restrict__ out1)
{
  __shared__ __align__(16) unsigned short LAh[128*32];
  __shared__ __align__(16) unsigned short LAl[128*32];
  __shared__ __align__(16) unsigned short LBh[128*32];
  __shared__ __align__(16) unsigned short LBl[128*32];

  const int t = threadIdx.x;
  const int wave = t >> 6, lane = t & 63;
  const int m0 = blockIdx.y * 128;
  const int n0 = blockIdx.x * 128;
  const int wr = wave >> 1, wc = wave & 1;
  const int ln = lane & 15, kq = lane >> 4;
  const int srow = lane >> 2;          // staging: row within 16-row group
  const int scol = (lane & 3) * 8;     // staging: col (elements)

  f32x4 acc[4][4];
  #pragma unroll
  for (int i = 0; i < 4; ++i)
    #pragma unroll
    for (int j = 0; j < 4; ++j) acc[i][j] = (f32x4){0.f, 0.f, 0.f, 0.f};

  const unsigned short* pAh = Ah_g + (size_t)m0 * 1024;
  const unsigned short* pAl = Al_g + (size_t)m0 * 1024;
  const unsigned short* pBh = Bh_g + (size_t)n0 * 1024;
  const unsigned short* pBl = Bl_g + (size_t)n0 * 1024;

  auto stage = [&](const unsigned short* g, unsigned short* lds, int k0) {
    #pragma unroll
    for (int r = 0; r < 2; ++r) {
      const int row = r * 64 + wave * 16 + srow;
      const unsigned short* gp = g + (size_t)row * 1024 + k0 + scol;   // per-lane
      unsigned short* lp = lds + (r * 64 + wave * 16) * 32;            // wave-uniform
      __builtin_amdgcn_global_load_lds((const __attribute__((address_space(1))) void*)gp,
                                       (__attribute__((address_space(3))) void*)lp,
                                       16, 0, 0);
    }
  };

  for (int k0 = 0; k0 < 1024; k0 += 32) {
    __syncthreads();
    stage(pAh, LAh, k0);
    stage(pAl, LAl, k0);
    stage(pBh, LBh, k0);
    stage(pBl, LBl, k0);
    __syncthreads();

    bf16x8 ah[4], al[4], bh[4], bl[4];
    #pragma unroll
    for (int i = 0; i < 4; ++i) {
      const int ar = (wr * 64 + i * 16 + ln) * 32 + kq * 8;
      const int br = (wc * 64 + i * 16 + ln) * 32 + kq * 8;
      ah[i] = *(const bf16x8*)&LAh[ar];
      al[i] = *(const bf16x8*)&LAl[ar];
      bh[i] = *(const bf16x8*)&LBh[br];
      bl[i] = *(const bf16x8*)&LBl[br];
    }
    #pragma unroll
    for (int i = 0; i < 4; ++i)
      #pragma unroll
      for (int j = 0; j < 4; ++j) {
        acc[i][j] = __builtin_amdgcn_mfma_f32_16x16x32_bf16(ah[i], bh[j], acc[i][j], 0, 0, 0);
        acc[i][j] = __builtin_amdgcn_mfma_f32_16x16x32_bf16(ah[i], bl[j], acc[i][j], 0, 0, 0);
        acc[i][j] = __builtin_amdgcn_mfma_f32_16x16x32_bf16(al[i], bh[j], acc[i][j], 0, 0, 0);
      }
  }

  // Epilogue. C/D layout: col = lane&15, row = (lane>>4)*4 + reg  [m89/m91]
  if (MODE == 0) {
    #pragma unroll
    for (int nj = 0; nj < 4; ++nj) {
      const int col = n0 + wc * 64 + nj * 16 + ln;
      const float bv = bias[col];
      #pragma unroll
      for (int mi = 0; mi < 4; ++mi) {
        const int row = m0 + wr * 64 + mi * 16 + kq * 4;
        #pragma unroll
        for (int j = 0; j < 4; ++j)
          out0[(size_t)(row + j) * 2048 + col] = acc[mi][nj][j] + bv;
      }
    }
  } else {
    const bool isB = (blockIdx.x == 8);
    if (!isB) {
      #pragma unroll
      for (int nj = 0; nj < 4; ++nj) {
        const int col = n0 + wc * 64 + nj * 16 + ln;
        #pragma unroll
        for (int mi = 0; mi < 4; ++mi) {
          const int row = m0 + wr * 64 + mi * 16 + kq * 4;
          #pragma unroll
          for (int j = 0; j < 4; ++j)
            out0[(size_t)(row + j) * 1024 + col] = softplus_f(acc[mi][nj][j]);
        }
      }
    } else {
      #pragma unroll
      for (int nj = 0; nj < 4; ++nj) {
        const int col = wc * 64 + nj * 16 + ln;     // 0..127
        const float bv = bias[col];
        #pragma unroll
        for (int mi = 0; mi < 4; ++mi) {
          const int row = m0 + wr * 64 + mi * 16 + kq * 4;
          #pragma unroll
          for (int j = 0; j < 4; ++j)
            out1[(size_t)(row + j) * 128 + col] = acc[mi][nj][j] + bv;
        }
      }
    }
  }
}

// ---------------------------------------------------------------------------
// Depthwise causal conv (K=4) + silu. Reads u = xp[:, :1024], writes uc (d_out).
// ---------------------------------------------------------------------------
__global__ void k_conv(const float* __restrict__ xp, const float* __restrict__ cw,
    const float* __restrict__ cb, float* __restrict__ uc)
{
  const int e = blockIdx.x * 256 + threadIdx.x;   // [0, 4096*1024)
  const int m = e >> 10;
  const int d = e & 1023;
  const int l = m & (LTOT - 1);
  float a = cb[d];
  #pragma unroll
  for (int j = 0; j < 4; ++j) {
    const int lj = l - 3 + j;
    if (lj >= 0)
      a = fmaf(xp[(size_t)(m - 3 + j) * 2048 + d], cw[d*4 + j], a);
  }
  uc[e] = a / (1.f + expf(-a));
}

// ---------------------------------------------------------------------------
// Chunk-parallel selective scan (A: local scan, B: combine, C: recompute+emit)
// ---------------------------------------------------------------------------
#define SPAD 20

__global__ __launch_bounds__(256) void k_scanA(
    const float* __restrict__ delta, const float* __restrict__ uc,
    const float* __restrict__ Bm, const float* __restrict__ a_log,
    float* __restrict__ hend, float* __restrict__ Pp)
{
  __shared__ float sd[CHK][SPAD];
  __shared__ float su[CHK][SPAD];
  __shared__ float sb[CHK][SPAD];
  const int t = threadIdx.x;
  const int bid = blockIdx.x;
  const int dblk = bid & 63;
  const int ch   = (bid >> 6) & (NCH - 1);
  const int b    = bid >> 11;
  const int d0 = dblk * 16;
  const int g  = dblk >> 3;
  const int l0 = ch * CHK;
  const size_t mb = (size_t)b * LTOT;

  {
    const int lrow = t >> 2;
    const int lc4  = (t & 3) * 4;
    const size_t r = mb + l0 + lrow;
    float4 rd = *(const float4*)&delta[r*1024 + d0 + lc4];
    float4 ru = *(const float4*)&uc[r*1024 + d0 + lc4];
    float4 rb = *(const float4*)&Bm[r*128 + g*16 + lc4];
    *(float4*)&sd[lrow][lc4] = rd;
    *(float4*)&su[lrow][lc4] = ru;
    *(float4*)&sb[lrow][lc4] = rb;
  }
  __syncthreads();

  const int gi = t >> 4;
  const int n  = t & 15;
  const int d  = d0 + gi;
  const float A2 = -expf(a_log[d*16 + n]) * 1.4426950408889634f;

  float h = 0.f, P = 1.f;
  #pragma unroll 8
  for (int l = 0; l < CHK; ++l) {
    const float dv = sd[l][gi];
    const float uv = su[l][gi];
    const float bv = sb[l][n];
    const float da = exp2f(dv * A2);
    P *= da;
    h = fmaf(da, h, dv * uv * bv);
  }
  const size_t idx = ((size_t)(b*NCH + ch) * 1024 + d) * 16 + n;
  hend[idx] = h;
  Pp[idx]   = P;
}

__global__ void k_scanB(float* hP, const float* __restrict__ Pp)
{
  const int t = blockIdx.x * 256 + threadIdx.x;   // 32768 strands
  const int b  = t >> 14;
  const int dn = t & 16383;
  float H = 0.f;
  for (int ch = 0; ch < NCH; ++ch) {
    const size_t idx = ((size_t)(b*NCH + ch) << 14) + dn;
    const float he = hP[idx];
    const float P  = Pp[idx];
    hP[idx] = H;
    H = fmaf(P, H, he);
  }
}

__global__ __launch_bounds__(256) void k_scanC(
    const float* __restrict__ xp, const float* __restrict__ delta,
    const float* __restrict__ uc, const float* __restrict__ Bm,
    const float* __restrict__ a_log, const float* __restrict__ cp,
    const float* __restrict__ Hstart, float* __restrict__ out)
{
  __shared__ float sd[CHK][SPAD];
  __shared__ float su[CHK][SPAD];
  __shared__ float sb[CHK][SPAD];
  __shared__ float sv[CHK][SPAD];
  __shared__ float sy[CHK][SPAD];
  const int t = threadIdx.x;
  const int bid = blockIdx.x;
  const int dblk = bid & 63;
  const int ch   = (bid >> 6) & (NCH - 1);
  const int b    = bid >> 11;
  const int d0 = dblk * 16;
  const int g  = dblk >> 3;
  const int l0 = ch * CHK;
  const size_t mb = (size_t)b * LTOT;

  {
    const int lrow = t >> 2;
    const int lc4  = (t & 3) * 4;
    const size_t r = mb + l0 + lrow;
    float4 rd = *(const float4*)&delta[r*1024 + d0 + lc4];
    float4 ru = *(const float4*)&uc[r*1024 + d0 + lc4];
    float4 rv = *(const float4*)&xp[r*2048 + 1024 + d0 + lc4];
    float4 rb = *(const float4*)&Bm[r*128 + g*16 + lc4];
    *(float4*)&sd[lrow][lc4] = rd;
    *(float4*)&su[lrow][lc4] = ru;
    *(float4*)&sv[lrow][lc4] = rv;
    *(float4*)&sb[lrow][lc4] = rb;
  }
  __syncthreads();

  const int gi = t >> 4;
  const int n  = t & 15;
  const int d  = d0 + gi;
  const float A2 = -expf(a_log[d*16 + n]) * 1.4426950408889634f;
  const float cc = cp[d*16 + n];
  float h = Hstart[((size_t)(b*NCH + ch) * 1024 + d) * 16 + n];

  #pragma unroll
  for (int l16 = 0; l16 < CHK; l16 += 16) {
    float p[16];
    #pragma unroll
    for (int j = 0; j < 16; ++j) {
      const int l = l16 + j;
      const float dv = sd[l][gi];
      const float uv = su[l][gi];
      const float bv = sb[l][n];
      const float da = exp2f(dv * A2);
      h = fmaf(da, h, dv * uv * bv);
      p[j] = h * cc;
    }
    float q8[8];
    #pragma unroll
    for (int j = 0; j < 8; ++j) {
      const float send = (n & 8) ? p[j]     : p[j + 8];
      const float keep = (n & 8) ? p[j + 8] : p[j];
      q8[j] = keep + __shfl_xor(send, 8, 16);
    }
    float q4[4];
    #pragma unroll
    for (int j = 0; j < 4; ++j) {
      const float send = (n & 4) ? q8[j]     : q8[j + 4];
      const float keep = (n & 4) ? q8[j + 4] : q8[j];
      q4[j] = keep + __shfl_xor(send, 4, 16);
    }
    float q2[2];
    #pragma unroll
    for (int j = 0; j < 2; ++j) {
      const float send = (n & 2) ? q4[j]     : q4[j + 2];
      const float keep = (n & 2) ? q4[j + 2] : q4[j];
      q2[j] = keep + __shfl_xor(send, 2, 16);
    }
    {
      const float send = (n & 1) ? q2[0] : q2[1];
      const float keep = (n & 1) ? q2[1] : q2[0];
      sy[l16 + n][gi] = keep + __shfl_xor(send, 1, 16);
    }
  }

  __syncthreads();
  const int rr = t >> 4;
  const int c  = t & 15;
  #pragma unroll
  for (int k = 0; k < 4; ++k) {
    const int r = rr + k * 16;
    const float vv = sv[r][c];
    out[(mb + l0 + r) * 1024 + d0 + c] = sy[r][c] * (vv / (1.f + expf(-vv)));
  }
}

// ---------------------------------------------------------------------------
extern "C" void kernel_launch(void* const* d_in, const int* in_sizes, int n_in,
                              void* d_out, int out_size, void* d_ws, size_t ws_size,
                              hipStream_t stream) {
  const float* x    = (const float*)d_in[0];
  const float* w1   = (const float*)d_in[1];
  const float* b1   = (const float*)d_in[2];
  const float* dw   = (const float*)d_in[3];
  const float* alog = (const float*)d_in[4];
  const float* bw   = (const float*)d_in[5];
  const float* bb   = (const float*)d_in[6];
  const float* cp   = (const float*)d_in[7];
  const float* cw   = (const float*)d_in[8];
  const float* cb   = (const float*)d_in[9];
  float* out = (float*)d_out;

  float* xp    = (float*)d_ws;                        // [4096][2048]  32 MB
  float* delta = xp + (size_t)MROWS * 2048;           // [4096][1024]  16 MB
  float* Bm    = delta + (size_t)MROWS * 1024;        // [4096][128]    2 MB
  float* hend  = Bm + (size_t)MROWS * 128;            // 4 MB (also Hstart)
  float* Pp    = hend + (size_t)2 * NCH * 1024 * 16;  // 4 MB
  unsigned short* xh   = (unsigned short*)(Pp + (size_t)2 * NCH * 1024 * 16);
  unsigned short* xl   = xh   + (size_t)MROWS * 1024;   // xh/xl reused as uh/ul
  unsigned short* w1h  = xl   + (size_t)MROWS * 1024;
  unsigned short* w1l  = w1h  + (size_t)2048 * 1024;
  unsigned short* wdbh = w1l  + (size_t)2048 * 1024;
  unsigned short* wdbl = wdbh + (size_t)1152 * 1024;

  // split conversions
  k_cvt<<<(MROWS*1024/4 + 255)/256, 256, 0, stream>>>(x,  xh,  xl,  MROWS*1024/4);
  k_cvt<<<(2048*1024/4 + 255)/256, 256, 0, stream>>>(w1, w1h, w1l, 2048*1024/4);
  k_cvt<<<(1024*1024/4 + 255)/256, 256, 0, stream>>>(dw, wdbh, wdbl, 1024*1024/4);
  k_cvt<<<(128*1024/4  + 255)/256, 256, 0, stream>>>(bw, wdbh + (size_t)1024*1024,
                                                         wdbl + (size_t)1024*1024, 128*1024/4);
  // GEMM1: xp = x @ W_in^T + b
  k_gemm<0><<<dim3(16, 32), 256, 0, stream>>>(xh, xl, w1h, w1l, b1, xp, nullptr);
  // u -> hi/lo
  k_cvt_u<<<MROWS*256/256, 256, 0, stream>>>(xp, xh, xl);
  // GEMM2: delta = softplus(u @ Wd^T), Bm = u @ Wb^T + bb
  k_gemm<1><<<dim3(9, 32), 256, 0, stream>>>(xh, xl, wdbh, wdbl, bb, delta, Bm);
  // conv + silu -> out (uc)
  k_conv<<<(MROWS * 1024) / 256, 256, 0, stream>>>(xp, cw, cb, out);
  // chunk-parallel scan
  k_scanA<<<2 * NCH * 64, 256, 0, stream>>>(delta, out, Bm, alog, hend, Pp);
  k_scanB<<<128, 256, 0, stream>>>(hend, Pp);
  k_scanC<<<2 * NCH * 64, 256, 0, stream>>>(xp, delta, out, Bm, alog, cp, hend, out);
}